// Round 17
// baseline (34.934 us; speedup 1.0000x reference)
//
#include <hip/hip_runtime.h>

#define RADIUS2 0.01f
#define NS 32
#define B_ 4
#define M_ 2048
#define N_ 8192
#define C_ 64
#define OUTW 67               // 3 + C
#define PERQ (NS * OUTW)      // 2144 floats per query (8576 B)
#define PERQ4 (PERQ / 4)      // 536 aligned f32x4 per query
#define GD 10                 // cells per axis (cell width = radius)
#define NC (GD * GD * GD)     // 1000
#define CAP 128               // max candidates (Poisson(34); P(>128) ~ 1e-33)
#define ROWW 68               // LDS row stride: pad,xyz,64 feats

typedef float f32x4 __attribute__((ext_vector_type(4)));

__device__ __forceinline__ int clamp9(int v) { return v < 0 ? 0 : (v > 9 ? 9 : v); }

// ---- build pass 1: per-batch LDS hist + scan (1 block/batch); zeroes gfill ----
__global__ __launch_bounds__(1024) void hist_scan(
    const float* __restrict__ pointset, int* __restrict__ cellstart,
    int* __restrict__ gfill)
{
    const int b   = blockIdx.x;
    const int tid = threadIdx.x;
    const float* __restrict__ ps = pointset + (size_t)b * N_ * 3;
    int* __restrict__ cs = cellstart + b * (NC + 1);

    __shared__ int scnt[NC];
    for (int c = tid; c < NC; c += 1024) { scnt[c] = 0; gfill[b * NC + c] = 0; }
    __syncthreads();

    for (int i = tid; i < N_; i += 1024) {
        const int cx = clamp9((int)(ps[i*3+0] * 10.f));
        const int cy = clamp9((int)(ps[i*3+1] * 10.f));
        const int cz = clamp9((int)(ps[i*3+2] * 10.f));
        atomicAdd(&scnt[(cz * GD + cy) * GD + cx], 1);
    }
    __syncthreads();

    int cnt = 0;
    if (tid < NC) cnt = scnt[tid];
    for (int off = 1; off < NC; off <<= 1) {   // inclusive Hillis-Steele
        int v = 0;
        if (tid < NC && tid >= off) v = scnt[tid - off];
        __syncthreads();
        if (tid < NC) scnt[tid] += v;
        __syncthreads();
    }
    if (tid < NC) cs[tid] = scnt[tid] - cnt;   // exclusive
    if (tid == 0) cs[NC] = N_;
}

// ---- build pass 2: parallel scatter into cell order (128 blocks) ----
__global__ __launch_bounds__(256) void scatter_kernel(
    const float* __restrict__ pointset, const int* __restrict__ cellstart,
    int* __restrict__ gfill, float4* __restrict__ sorted4)
{
    const int gid = blockIdx.x * 256 + threadIdx.x;      // [0, B*N)
    const int b = gid >> 13, i = gid & (N_ - 1);         // N = 8192 = 2^13
    const float x = pointset[(size_t)gid * 3 + 0];
    const float y = pointset[(size_t)gid * 3 + 1];
    const float z = pointset[(size_t)gid * 3 + 2];
    const int c = (clamp9((int)(z * 10.f)) * GD + clamp9((int)(y * 10.f))) * GD
                  + clamp9((int)(x * 10.f));
    const int pos = cellstart[b * (NC + 1) + c] + atomicAdd(&gfill[b * NC + c], 1);
    sorted4[(size_t)b * N_ + pos] = make_float4(x, y, z, __int_as_float(i));
}

// ---- query + group: R16 winner + sphere-slab row culling/x-trim ----
__global__ __launch_bounds__(256, 4) void query_group(
    const float* __restrict__ new_xyz, const float* __restrict__ pointset,
    const float* __restrict__ feature, const int* __restrict__ cellstart,
    const float4* __restrict__ sorted4, float* __restrict__ out)
{
    const int w    = threadIdx.x >> 6;
    const int lane = threadIdx.x & 63;
    const int bid  = blockIdx.x;
    const int swz  = (bid & 7) * 256 + (bid >> 3);       // bijective XCD swizzle
    const int q    = swz * 4 + w;
    const int b    = q >> 11;            // q / M

    __shared__ __align__(16) float srow[4][NS * ROWW];   // 8704 B per wave
    __shared__ f32x4 sfin4[4][NS];

    float* __restrict__ srw   = srow[w];
    f32x4* __restrict__ cand4 = (f32x4*)srow[w];         // first 2 KB, dead after rank

    const float* __restrict__ ps   = pointset + (size_t)b * N_ * 3;
    const int* __restrict__ cs     = cellstart + b * (NC + 1);
    const float4* __restrict__ sp4 = sorted4 + (size_t)b * N_;

    const float qx = new_xyz[q*3+0];
    const float qy = new_xyz[q*3+1];
    const float qz = new_xyz[q*3+2];

    const int cy = clamp9((int)(qy * 10.f));
    const int cz = clamp9((int)(qz * 10.f));

    // 9 row-range bounds with sphere-slab culling + conservative x-trim.
    // Only provably-out-of-ball points are dropped: candidate SET shrinks,
    // ranked output identical.
    int rs[9], cum[10];
    cum[0] = 0;
#pragma unroll
    for (int dz = 0; dz < 3; ++dz) {
#pragma unroll
        for (int dy = 0; dy < 3; ++dy) {
            const int zz = cz + dz - 1, yy = cy + dy - 1;
            const int r  = dz * 3 + dy;
            int s = 0, e = 0;
            if (zz >= 0 && zz < GD && yy >= 0 && yy < GD) {
                const float ylo = yy * 0.1f, zlo = zz * 0.1f;
                const float dyv = qy < ylo ? ylo - qy
                                : (qy > ylo + 0.1f ? qy - (ylo + 0.1f) : 0.f);
                const float dzv = qz < zlo ? zlo - qz
                                : (qz > zlo + 0.1f ? qz - (zlo + 0.1f) : 0.f);
                const float dmin2 = dyv * dyv + dzv * dzv;
                if (dmin2 < RADIUS2 * 1.000001f) {       // row can touch the ball
                    float rem = RADIUS2 - dmin2;
                    if (rem < 0.f) rem = 0.f;
                    const float xr = sqrtf(rem) * 1.000002f + 1e-7f;  // padded
                    int xl = (int)((qx - xr) * 10.f); xl = xl < 0 ? 0 : xl;
                    int xh = (int)((qx + xr) * 10.f); xh = xh > 9 ? 9 : xh;
                    const int base = (zz * GD + yy) * GD;
                    s = cs[base + xl];
                    e = cs[base + xh + 1];
                }
            }
            rs[r]      = s;
            cum[r + 1] = cum[r] + (e - s);
        }
    }
    const int T = cum[9];                // total scanned points (~145 avg)

    // ---- phase 1 (FLAT): single loop, loads pipeline across iterations ----
    int ncand = 0;
    for (int base = 0; base < T; base += 64) {
        const int t   = base + lane;
        const bool act = t < T;
        const int tc  = act ? t : T - 1;
        int r = 0;                        // unrolled 8-compare range select
#pragma unroll
        for (int k = 1; k < 9; ++k) r += (tc >= cum[k]);
        const int j = rs[r] + (tc - cum[r]);
        const float4 v = sp4[j];
        const float dx = qx - v.x;
        const float dy = qy - v.y;
        const float dz = qz - v.z;
        // exact non-fma sum of squares (matches reference ties)
        const float d2 = __fadd_rn(__fadd_rn(__fmul_rn(dx,dx), __fmul_rn(dy,dy)),
                                   __fmul_rn(dz,dz));
        const bool in = act && (d2 < RADIUS2);
        const unsigned long long mk = __ballot(in);
        if (in) {
            const unsigned pre = __builtin_amdgcn_mbcnt_hi(
                (unsigned)(mk >> 32),
                __builtin_amdgcn_mbcnt_lo((unsigned)mk, 0u));
            const int slot = ncand + (int)pre;
            if (slot < CAP) cand4[slot] = (f32x4){v.x, v.y, v.z, v.w};
        }
        ncand += (int)__popcll(mk);
    }
    if (ncand > CAP) ncand = CAP;

    // ---- rank by original index -> first-32-in-index-order ----
    int i0 = 0x7fffffff, i1 = 0x7fffffff;
    f32x4 rec0, rec1;
    if (lane      < ncand) { rec0 = cand4[lane];      i0 = __float_as_int(rec0.w); }
    if (lane + 64 < ncand) { rec1 = cand4[lane + 64]; i1 = __float_as_int(rec1.w); }
    int r0 = 0, r1 = 0;
    for (int j = 0; j < ncand; ++j) {
        const int cj = __float_as_int(srw[j * 4 + 3]);  // broadcast read
        r0 += (cj < i0);
        r1 += (cj < i1);
    }
    const int cnt = ncand < NS ? ncand : NS;
    if (i0 != 0x7fffffff && r0 < NS) sfin4[w][r0] = rec0;
    if (i1 != 0x7fffffff && r1 < NS) sfin4[w][r1] = rec1;
    if (ncand == 0 && lane == 0)     // CUDA semantics: no neighbor -> point 0
        sfin4[w][0] = (f32x4){ps[0], ps[1], ps[2], __int_as_float(0)};
    if (lane < NS && lane >= cnt) sfin4[w][lane] = sfin4[w][0];

    // ---- phase 2a: build rows in LDS (cand region now dead) ----
    if (lane < NS) {
        const f32x4 v = sfin4[w][lane];
        f32x4 head = {0.f, v.x - qx, v.y - qy, v.z - qz};
        *(f32x4*)(srw + lane * ROWW) = head;             // aligned b128
    }
    const float* __restrict__ fb = feature + (size_t)b * N_ * C_;
#pragma unroll
    for (int h = 0; h < 8; ++h) {
        const int item = h * 64 + lane;                  // 32 samples x 16 chunks
        const int sv = item >> 4;
        const int kv = item & 15;
        const int iv = __float_as_int(sfin4[w][sv].w);
        const f32x4 d = *(const f32x4*)(fb + (size_t)iv * C_ + kv * 4);  // coalesced
        *(f32x4*)(srw + sv * ROWW + 4 + kv * 4) = d;     // aligned b128
    }

    // ---- phase 2b: aligned f32x4 nt-stores from LDS ----
    f32x4* __restrict__ outq4 = (f32x4*)(out + (size_t)q * PERQ);
    for (int o4 = lane; o4 < PERQ4; o4 += 64) {
        const int o   = o4 * 4;
        const int s0  = (o * 1957) >> 17;                // exact /67 on [0,2144)
        const int thr = 67 * s0 + 67 - o;
        f32x4 v;
#pragma unroll
        for (int e = 0; e < 4; ++e) {
            const int inc = (e >= thr) ? 1 : 0;          // skip row pad on crossing
            v[e] = srw[o + e + s0 + 1 + inc];
        }
        __builtin_nontemporal_store(v, outq4 + o4);      // full-line tiling
    }
}

// ---- tier-3 fallback (R3 kernel) if ws too small ----
#define NWF 8
#define TILEF 1024
#define NTILEF (N_ / TILEF)

__global__ __launch_bounds__(NWF * 64) void ballquery_fallback(
    const float* __restrict__ new_xyz, const float* __restrict__ pointset,
    const float* __restrict__ feature, float* __restrict__ out)
{
    const int tid  = threadIdx.x;
    const int w    = tid >> 6;
    const int lane = tid & 63;
    const int q    = blockIdx.x * NWF + w;
    const int b    = q >> 11;

    __shared__ float4 spts[TILEF];
    __shared__ int    sidx[NWF][NS];
    __shared__ int    s_done;

    const float qx = new_xyz[q*3+0], qy = new_xyz[q*3+1], qz = new_xyz[q*3+2];
    const float* __restrict__ ps = pointset + (size_t)b * N_ * 3;

    if (tid == 0) s_done = 0;
    int cnt = 0; bool counted = false;

    for (int t = 0; t < NTILEF; ++t) {
        __syncthreads();
        if (s_done == NWF) break;
        {
            const float* __restrict__ tp = ps + t * TILEF * 3;
            float* __restrict__ sp = (float*)spts;
            for (int d = tid; d < TILEF * 3; d += NWF * 64) {
                const int p = d / 3;
                sp[p * 4 + (d - p * 3)] = tp[d];
            }
        }
        __syncthreads();
        if (cnt < NS) {
#pragma unroll 4
            for (int it = 0; it < TILEF / 64; ++it) {
                const float4 p = spts[it * 64 + lane];
                const float dx = qx - p.x, dy = qy - p.y, dz = qz - p.z;
                const float d2 = __fadd_rn(__fadd_rn(__fmul_rn(dx,dx), __fmul_rn(dy,dy)),
                                           __fmul_rn(dz,dz));
                const bool in = d2 < RADIUS2;
                const unsigned long long mk = __ballot(in);
                const unsigned pre = __builtin_amdgcn_mbcnt_hi(
                    (unsigned)(mk >> 32), __builtin_amdgcn_mbcnt_lo((unsigned)mk, 0u));
                if (in) {
                    const int slot = cnt + (int)pre;
                    if (slot < NS) sidx[w][slot] = t * TILEF + it * 64 + lane;
                }
                cnt += (int)__popcll(mk);
            }
        }
        if (!counted && cnt >= NS) { counted = true; if (lane == 0) atomicAdd(&s_done, 1); }
    }
    if (cnt > NS) cnt = NS;
    const int first = (cnt > 0) ? sidx[w][0] : 0;
    if (lane < NS && lane >= cnt) sidx[w][lane] = first;

    const float* __restrict__ fb = feature + (size_t)b * N_ * C_;
    float* __restrict__ outq = out + (size_t)q * PERQ;
    int s = 0, c = lane;
    for (int o = lane; o < PERQ; o += 64) {
        const int i = sidx[w][s];
        float v;
        if (c < 3) v = ps[i*3+c] - new_xyz[q*3+c];
        else       v = fb[(size_t)i * C_ + (c - 3)];
        outq[o] = v;
        c += 64;
        if (c >= OUTW) { c -= OUTW; s += 1; }
    }
}

extern "C" void kernel_launch(void* const* d_in, const int* in_sizes, int n_in,
                              void* d_out, int out_size, void* d_ws, size_t ws_size,
                              hipStream_t stream) {
    const float* new_xyz  = (const float*)d_in[0];
    const float* pointset = (const float*)d_in[1];
    const float* feature  = (const float*)d_in[2];
    float* out = (float*)d_out;

    // ws layout: sorted4 | cellstart | gfill
    const size_t s4_bytes = (size_t)B_ * N_ * sizeof(float4);      // 524288
    const size_t cs_bytes = (size_t)B_ * (NC + 1) * sizeof(int);   // 16016
    const size_t gf_bytes = (size_t)B_ * NC * sizeof(int);         // 16000
    const size_t needed   = s4_bytes + cs_bytes + gf_bytes;

    if (ws_size >= needed) {
        float4* sorted4   = (float4*)d_ws;
        int*    cellstart = (int*)((char*)d_ws + s4_bytes);
        int*    gfill     = (int*)((char*)d_ws + s4_bytes + cs_bytes);

        hist_scan<<<B_, 1024, 0, stream>>>(pointset, cellstart, gfill);
        scatter_kernel<<<(B_ * N_) / 256, 256, 0, stream>>>(
            pointset, cellstart, gfill, sorted4);
        query_group<<<(B_ * M_) / 4, 256, 0, stream>>>(
            new_xyz, pointset, feature, cellstart, sorted4, out);
    } else {
        ballquery_fallback<<<(B_ * M_) / NWF, NWF * 64, 0, stream>>>(
            new_xyz, pointset, feature, out);
    }
}

// Round 18
// 32.971 us; speedup vs baseline: 1.0595x; 1.0595x over previous
//
#include <hip/hip_runtime.h>

#define RADIUS2 0.01f
#define NS 32
#define B_ 4
#define M_ 2048
#define N_ 8192
#define C_ 64
#define OUTW 67               // 3 + C
#define PERQ (NS * OUTW)      // 2144 floats per query (8576 B)
#define PERQ4 (PERQ / 4)      // 536 aligned f32x4 per query
#define GD 10                 // cells per axis (cell width = radius)
#define NC (GD * GD * GD)     // 1000
#define CAP 128               // max candidates (Poisson(34); P(>128) ~ 1e-33)
#define ROWW 68               // LDS row stride: pad,xyz,64 feats

typedef float f32x4 __attribute__((ext_vector_type(4)));

__device__ __forceinline__ int clamp9(int v) { return v < 0 ? 0 : (v > 9 ? 9 : v); }

// ---- build pass 1: per-batch LDS hist + scan (1 block/batch); zeroes gfill ----
__global__ __launch_bounds__(1024) void hist_scan(
    const float* __restrict__ pointset, int* __restrict__ cellstart,
    int* __restrict__ gfill)
{
    const int b   = blockIdx.x;
    const int tid = threadIdx.x;
    const float* __restrict__ ps = pointset + (size_t)b * N_ * 3;
    int* __restrict__ cs = cellstart + b * (NC + 1);

    __shared__ int scnt[NC];
    for (int c = tid; c < NC; c += 1024) { scnt[c] = 0; gfill[b * NC + c] = 0; }
    __syncthreads();

    for (int i = tid; i < N_; i += 1024) {
        const int cx = clamp9((int)(ps[i*3+0] * 10.f));
        const int cy = clamp9((int)(ps[i*3+1] * 10.f));
        const int cz = clamp9((int)(ps[i*3+2] * 10.f));
        atomicAdd(&scnt[(cz * GD + cy) * GD + cx], 1);
    }
    __syncthreads();

    int cnt = 0;
    if (tid < NC) cnt = scnt[tid];
    for (int off = 1; off < NC; off <<= 1) {   // inclusive Hillis-Steele
        int v = 0;
        if (tid < NC && tid >= off) v = scnt[tid - off];
        __syncthreads();
        if (tid < NC) scnt[tid] += v;
        __syncthreads();
    }
    if (tid < NC) cs[tid] = scnt[tid] - cnt;   // exclusive
    if (tid == 0) cs[NC] = N_;
}

// ---- build pass 2: parallel scatter into cell order (128 blocks) ----
__global__ __launch_bounds__(256) void scatter_kernel(
    const float* __restrict__ pointset, const int* __restrict__ cellstart,
    int* __restrict__ gfill, float4* __restrict__ sorted4)
{
    const int gid = blockIdx.x * 256 + threadIdx.x;      // [0, B*N)
    const int b = gid >> 13, i = gid & (N_ - 1);         // N = 8192 = 2^13
    const float x = pointset[(size_t)gid * 3 + 0];
    const float y = pointset[(size_t)gid * 3 + 1];
    const float z = pointset[(size_t)gid * 3 + 2];
    const int c = (clamp9((int)(z * 10.f)) * GD + clamp9((int)(y * 10.f))) * GD
                  + clamp9((int)(x * 10.f));
    const int pos = cellstart[b * (NC + 1) + c] + atomicAdd(&gfill[b * NC + c], 1);
    sorted4[(size_t)b * N_ + pos] = make_float4(x, y, z, __int_as_float(i));
}

// ---- query + group: R16 winner (flat pipelined phase-1, srow bridge) ----
__global__ __launch_bounds__(256, 4) void query_group(
    const float* __restrict__ new_xyz, const float* __restrict__ pointset,
    const float* __restrict__ feature, const int* __restrict__ cellstart,
    const float4* __restrict__ sorted4, float* __restrict__ out)
{
    const int w    = threadIdx.x >> 6;
    const int lane = threadIdx.x & 63;
    const int bid  = blockIdx.x;
    const int swz  = (bid & 7) * 256 + (bid >> 3);       // bijective XCD swizzle
    const int q    = swz * 4 + w;
    const int b    = q >> 11;            // q / M

    __shared__ __align__(16) float srow[4][NS * ROWW];   // 8704 B per wave
    __shared__ f32x4 sfin4[4][NS];

    float* __restrict__ srw   = srow[w];
    f32x4* __restrict__ cand4 = (f32x4*)srow[w];         // first 2 KB, dead after rank

    const float* __restrict__ ps   = pointset + (size_t)b * N_ * 3;
    const int* __restrict__ cs     = cellstart + b * (NC + 1);
    const float4* __restrict__ sp4 = sorted4 + (size_t)b * N_;

    const float qx = new_xyz[q*3+0];
    const float qy = new_xyz[q*3+1];
    const float qz = new_xyz[q*3+2];

    const int cx = clamp9((int)(qx * 10.f));
    const int cy = clamp9((int)(qy * 10.f));
    const int cz = clamp9((int)(qz * 10.f));
    const int x0 = cx > 0 ? cx - 1 : 0, x1 = cx < 9 ? cx + 1 : 9;

    // prefetch 9 row-range bounds; build flat cumulative offsets
    int rs[9], cum[10];
    cum[0] = 0;
#pragma unroll
    for (int dz = 0; dz < 3; ++dz) {
#pragma unroll
        for (int dy = 0; dy < 3; ++dy) {
            const int zz = cz + dz - 1, yy = cy + dy - 1;
            const int r  = dz * 3 + dy;
            int s = 0, e = 0;
            if (zz >= 0 && zz < GD && yy >= 0 && yy < GD) {
                const int base = (zz * GD + yy) * GD;
                s = cs[base + x0];
                e = cs[base + x1 + 1];
            }
            rs[r]      = s;
            cum[r + 1] = cum[r] + (e - s);
        }
    }
    const int T = cum[9];                // total candidate points (~600 avg)

    // ---- phase 1 (FLAT): single loop, loads pipeline across iterations ----
    int ncand = 0;
    for (int base = 0; base < T; base += 64) {
        const int t   = base + lane;
        const bool act = t < T;
        const int tc  = act ? t : T - 1;
        int r = 0;                        // unrolled 8-compare range select
#pragma unroll
        for (int k = 1; k < 9; ++k) r += (tc >= cum[k]);
        const int j = rs[r] + (tc - cum[r]);
        const float4 v = sp4[j];
        const float dx = qx - v.x;
        const float dy = qy - v.y;
        const float dz = qz - v.z;
        // exact non-fma sum of squares (matches reference ties)
        const float d2 = __fadd_rn(__fadd_rn(__fmul_rn(dx,dx), __fmul_rn(dy,dy)),
                                   __fmul_rn(dz,dz));
        const bool in = act && (d2 < RADIUS2);
        const unsigned long long mk = __ballot(in);
        if (in) {
            const unsigned pre = __builtin_amdgcn_mbcnt_hi(
                (unsigned)(mk >> 32),
                __builtin_amdgcn_mbcnt_lo((unsigned)mk, 0u));
            const int slot = ncand + (int)pre;
            if (slot < CAP) cand4[slot] = (f32x4){v.x, v.y, v.z, v.w};
        }
        ncand += (int)__popcll(mk);
    }
    if (ncand > CAP) ncand = CAP;

    // ---- rank by original index -> first-32-in-index-order ----
    int i0 = 0x7fffffff, i1 = 0x7fffffff;
    f32x4 rec0, rec1;
    if (lane      < ncand) { rec0 = cand4[lane];      i0 = __float_as_int(rec0.w); }
    if (lane + 64 < ncand) { rec1 = cand4[lane + 64]; i1 = __float_as_int(rec1.w); }
    int r0 = 0, r1 = 0;
    for (int j = 0; j < ncand; ++j) {
        const int cj = __float_as_int(srw[j * 4 + 3]);  // broadcast read
        r0 += (cj < i0);
        r1 += (cj < i1);
    }
    const int cnt = ncand < NS ? ncand : NS;
    if (i0 != 0x7fffffff && r0 < NS) sfin4[w][r0] = rec0;
    if (i1 != 0x7fffffff && r1 < NS) sfin4[w][r1] = rec1;
    if (ncand == 0 && lane == 0)     // CUDA semantics: no neighbor -> point 0
        sfin4[w][0] = (f32x4){ps[0], ps[1], ps[2], __int_as_float(0)};
    if (lane < NS && lane >= cnt) sfin4[w][lane] = sfin4[w][0];

    // ---- phase 2a: build rows in LDS (cand region now dead) ----
    if (lane < NS) {
        const f32x4 v = sfin4[w][lane];
        f32x4 head = {0.f, v.x - qx, v.y - qy, v.z - qz};
        *(f32x4*)(srw + lane * ROWW) = head;             // aligned b128
    }
    const float* __restrict__ fb = feature + (size_t)b * N_ * C_;
#pragma unroll
    for (int h = 0; h < 8; ++h) {
        const int item = h * 64 + lane;                  // 32 samples x 16 chunks
        const int sv = item >> 4;
        const int kv = item & 15;
        const int iv = __float_as_int(sfin4[w][sv].w);
        const f32x4 d = *(const f32x4*)(fb + (size_t)iv * C_ + kv * 4);  // coalesced
        *(f32x4*)(srw + sv * ROWW + 4 + kv * 4) = d;     // aligned b128
    }

    // ---- phase 2b: aligned f32x4 nt-stores from LDS ----
    f32x4* __restrict__ outq4 = (f32x4*)(out + (size_t)q * PERQ);
    for (int o4 = lane; o4 < PERQ4; o4 += 64) {
        const int o   = o4 * 4;
        const int s0  = (o * 1957) >> 17;                // exact /67 on [0,2144)
        const int thr = 67 * s0 + 67 - o;
        f32x4 v;
#pragma unroll
        for (int e = 0; e < 4; ++e) {
            const int inc = (e >= thr) ? 1 : 0;          // skip row pad on crossing
            v[e] = srw[o + e + s0 + 1 + inc];
        }
        __builtin_nontemporal_store(v, outq4 + o4);      // full-line tiling
    }
}

// ---- tier-3 fallback (R3 kernel) if ws too small ----
#define NWF 8
#define TILEF 1024
#define NTILEF (N_ / TILEF)

__global__ __launch_bounds__(NWF * 64) void ballquery_fallback(
    const float* __restrict__ new_xyz, const float* __restrict__ pointset,
    const float* __restrict__ feature, float* __restrict__ out)
{
    const int tid  = threadIdx.x;
    const int w    = tid >> 6;
    const int lane = tid & 63;
    const int q    = blockIdx.x * NWF + w;
    const int b    = q >> 11;

    __shared__ float4 spts[TILEF];
    __shared__ int    sidx[NWF][NS];
    __shared__ int    s_done;

    const float qx = new_xyz[q*3+0], qy = new_xyz[q*3+1], qz = new_xyz[q*3+2];
    const float* __restrict__ ps = pointset + (size_t)b * N_ * 3;

    if (tid == 0) s_done = 0;
    int cnt = 0; bool counted = false;

    for (int t = 0; t < NTILEF; ++t) {
        __syncthreads();
        if (s_done == NWF) break;
        {
            const float* __restrict__ tp = ps + t * TILEF * 3;
            float* __restrict__ sp = (float*)spts;
            for (int d = tid; d < TILEF * 3; d += NWF * 64) {
                const int p = d / 3;
                sp[p * 4 + (d - p * 3)] = tp[d];
            }
        }
        __syncthreads();
        if (cnt < NS) {
#pragma unroll 4
            for (int it = 0; it < TILEF / 64; ++it) {
                const float4 p = spts[it * 64 + lane];
                const float dx = qx - p.x, dy = qy - p.y, dz = qz - p.z;
                const float d2 = __fadd_rn(__fadd_rn(__fmul_rn(dx,dx), __fmul_rn(dy,dy)),
                                           __fmul_rn(dz,dz));
                const bool in = d2 < RADIUS2;
                const unsigned long long mk = __ballot(in);
                const unsigned pre = __builtin_amdgcn_mbcnt_hi(
                    (unsigned)(mk >> 32), __builtin_amdgcn_mbcnt_lo((unsigned)mk, 0u));
                if (in) {
                    const int slot = cnt + (int)pre;
                    if (slot < NS) sidx[w][slot] = t * TILEF + it * 64 + lane;
                }
                cnt += (int)__popcll(mk);
            }
        }
        if (!counted && cnt >= NS) { counted = true; if (lane == 0) atomicAdd(&s_done, 1); }
    }
    if (cnt > NS) cnt = NS;
    const int first = (cnt > 0) ? sidx[w][0] : 0;
    if (lane < NS && lane >= cnt) sidx[w][lane] = first;

    const float* __restrict__ fb = feature + (size_t)b * N_ * C_;
    float* __restrict__ outq = out + (size_t)q * PERQ;
    int s = 0, c = lane;
    for (int o = lane; o < PERQ; o += 64) {
        const int i = sidx[w][s];
        float v;
        if (c < 3) v = ps[i*3+c] - new_xyz[q*3+c];
        else       v = fb[(size_t)i * C_ + (c - 3)];
        outq[o] = v;
        c += 64;
        if (c >= OUTW) { c -= OUTW; s += 1; }
    }
}

extern "C" void kernel_launch(void* const* d_in, const int* in_sizes, int n_in,
                              void* d_out, int out_size, void* d_ws, size_t ws_size,
                              hipStream_t stream) {
    const float* new_xyz  = (const float*)d_in[0];
    const float* pointset = (const float*)d_in[1];
    const float* feature  = (const float*)d_in[2];
    float* out = (float*)d_out;

    // ws layout: sorted4 | cellstart | gfill
    const size_t s4_bytes = (size_t)B_ * N_ * sizeof(float4);      // 524288
    const size_t cs_bytes = (size_t)B_ * (NC + 1) * sizeof(int);   // 16016
    const size_t gf_bytes = (size_t)B_ * NC * sizeof(int);         // 16000
    const size_t needed   = s4_bytes + cs_bytes + gf_bytes;

    if (ws_size >= needed) {
        float4* sorted4   = (float4*)d_ws;
        int*    cellstart = (int*)((char*)d_ws + s4_bytes);
        int*    gfill     = (int*)((char*)d_ws + s4_bytes + cs_bytes);

        hist_scan<<<B_, 1024, 0, stream>>>(pointset, cellstart, gfill);
        scatter_kernel<<<(B_ * N_) / 256, 256, 0, stream>>>(
            pointset, cellstart, gfill, sorted4);
        query_group<<<(B_ * M_) / 4, 256, 0, stream>>>(
            new_xyz, pointset, feature, cellstart, sorted4, out);
    } else {
        ballquery_fallback<<<(B_ * M_) / NWF, NWF * 64, 0, stream>>>(
            new_xyz, pointset, feature, out);
    }
}